// Round 10
// baseline (85.534 us; speedup 1.0000x reference)
//
#include <hip/hip_runtime.h>

static constexpr int KM1     = 1048575;        // sampled elems kk in [0, KM1-1]
static constexpr int M_S     = 32;
static constexpr int J_IT    = 16;             // iters/wave, 128 elems each
static constexpr int SPANE   = 128 * J_IT;     // 2048 elems per chunk
static constexpr int NCHUNK  = 512;
static constexpr int OFF_MAX = 2 * (KM1 - 2);  // last safe float offset of a pair load
static constexpr int NBLK    = (NCHUNK / 4) * 32;   // 4096 blocks

typedef float f32x2 __attribute__((ext_vector_type(2)));
typedef float f32x4 __attribute__((ext_vector_type(4)));

#if __has_builtin(__builtin_amdgcn_logf)
__device__ __forceinline__ float flog2(float x) { return __builtin_amdgcn_logf(x); }
#else
__device__ __forceinline__ float flog2(float x) { float r; asm("v_log_f32 %0, %1" : "=v"(r) : "v"(x)); return r; }
#endif
#if __has_builtin(__builtin_amdgcn_exp2f)
__device__ __forceinline__ float fexp2(float x) { return __builtin_amdgcn_exp2f(x); }
#else
__device__ __forceinline__ float fexp2(float x) { float r; asm("v_exp_f32 %0, %1" : "=v"(r) : "v"(x)); return r; }
#endif

struct Raw { f32x2 ua, ub; f32x4 m4; };

__global__ void final_reduce_kernel(const float* __restrict__ ws, float* __restrict__ out) {
    constexpr float LN2 = 0.69314718055994530942f;
    const int lane = threadIdx.x & 63;
    const int wave = threadIdx.x >> 6;
    float v = 0.0f;
    #pragma unroll
    for (int j = 0; j < NBLK / 256; ++j) v += ws[threadIdx.x + 256 * j];
    #pragma unroll
    for (int off = 32; off >= 1; off >>= 1) v += __shfl_down(v, off);
    __shared__ float s4[4];
    if (lane == 0) s4[wave] = v;
    __syncthreads();
    if (threadIdx.x == 0)
        out[0] = (s4[0] + s4[1] + s4[2] + s4[3]) * (-LN2 / (float)M_S);
}

__global__ __launch_bounds__(256, 4) void terp_kernel(
    const float* __restrict__ x,
    const float* __restrict__ ms,
    const float* __restrict__ u,
    float* __restrict__ ws)
{
    const int lane  = threadIdx.x & 63;
    const int wave  = threadIdx.x >> 6;
    const int m     = blockIdx.x & 31;
    const int cg    = blockIdx.x >> 5;
    // Stagger each m-row's chunk schedule by m*16 chunks (256 KB address
    // phase) so the 32 co-resident same-group blocks don't sweep the same
    // DRAM channels in lockstep. Bijective per m.
    const int chunk = ((cg << 2) + wave + (m << 4)) & (NCHUNK - 1);

    constexpr float LN2  = 0.69314718055994530942f;
    constexpr float invT = 1.0f / (2.5f * 0.9999f);
    constexpr float c_ms = invT / LN2;

    const float* __restrict__ u_row = u + (size_t)m * (2 * KM1);
    const float* __restrict__ msp   = ms;
    const int off0 = chunk * (2 * SPANE) + lane * 4;

    float acc = 0.0f;   // log2 units

#define LOADJ(j, R) do { \
        const int off_ = min(off0 + 256 * (j), OFF_MAX); \
        (R).ua = *(const f32x2*)(u_row + off_); \
        (R).ub = *(const f32x2*)(u_row + off_ + 2); \
        (R).m4 = *(const f32x4*)(msp + off_); \
    } while (0)

#define CALC1(u0_, u1_, m0_, m1_, t) do { \
        const float a_ = flog2(-flog2(u0_)) - flog2(-flog2(u1_)); \
        (t) = fexp2(fmaf(c_ms, (m1_) - (m0_), invT * a_)); \
    } while (0)

#define CALC2(R, ta, tb) do { \
        CALC1((R).ua.x, (R).ua.y, (R).m4.x, (R).m4.y, ta); \
        CALC1((R).ub.x, (R).ub.y, (R).m4.z, (R).m4.w, tb); \
    } while (0)

#define CONSUME(ta, tb, taN) do { \
        const float r_ = (lane == 0) ? (taN) : (ta); \
        const float v_ = __shfl(r_, (lane + 1) & 63); \
        const float selfP_ = (1.0f + (ta)) * (1.0f + (tb)); \
        const float coupP_ = fmaf((ta), (tb), 1.0f) * fmaf((tb), v_, 1.0f); \
        acc = fmaf(-2.0f, flog2(selfP_), acc + flog2(coupP_)); \
    } while (0)

    Raw R0, R1, R2, R3;
    LOADJ(0, R0); LOADJ(1, R1); LOADJ(2, R2); LOADJ(3, R3);

    // rotate partner for iter 15: first elem of next chunk (wave-uniform);
    // for the last chunk this is the last sampled elem (kk = KM1-1).
    float t_edge;
    {
        const int kkE = min(SPANE * (chunk + 1), KM1 - 1);
        const f32x2 uE = *(const f32x2*)(u_row + 2 * kkE);
        const f32x2 mE = *(const f32x2*)(msp + 2 * kkE);
        CALC1(uE.x, uE.y, mE.x, mE.y, t_edge);
    }

    float ta_c, tb_c;
    CALC2(R0, ta_c, tb_c);

#define STEP(j, Rn, Rl) do { \
        float ta_n_, tb_n_; CALC2(Rn, ta_n_, tb_n_); \
        if ((j) + 4 < J_IT) LOADJ((j) + 4, Rl); \
        CONSUME(ta_c, tb_c, ta_n_); \
        ta_c = ta_n_; tb_c = tb_n_; \
    } while (0)

    STEP(0,  R1, R0);  STEP(1,  R2, R1);  STEP(2,  R3, R2);  STEP(3,  R0, R3);
    STEP(4,  R1, R0);  STEP(5,  R2, R1);  STEP(6,  R3, R2);  STEP(7,  R0, R3);
    STEP(8,  R1, R0);  STEP(9,  R2, R1);  STEP(10, R3, R2);  STEP(11, R0, R3);
    STEP(12, R1, R0);  STEP(13, R2, R1);  STEP(14, R3, R2);

    // j = 15
    if (chunk != NCHUNK - 1) {
        CONSUME(ta_c, tb_c, t_edge);
    } else {
        // Ragged tail: lane63's clamped pair duplicates (1048573, 1048574).
        // Contribution: self(b) only; rotate value = tb so lane62's second
        // coupling becomes the true (1048573, 1048574) pair.
        const bool l63 = (lane == 63);
        const float r_ = (lane == 0) ? t_edge : (l63 ? tb_c : ta_c);
        const float v_ = __shfl(r_, (lane + 1) & 63);
        const float selfP_ = l63 ? (1.0f + tb_c) : ((1.0f + ta_c) * (1.0f + tb_c));
        const float coupP_ = l63 ? 1.0f : (fmaf(ta_c, tb_c, 1.0f) * fmaf(tb_c, v_, 1.0f));
        acc = fmaf(-2.0f, flog2(selfP_), acc + flog2(coupP_));
    }

    // boundary numerators: log2(x0 + x1*t_first) and log2(x0 + x1*t_last)
    if (lane == 0 && chunk == 0) {
        const float x0 = x[0], x1 = x[1];
        const f32x2 u0 = *(const f32x2*)u_row;
        const f32x2 m0 = *(const f32x2*)msp;
        float t1; CALC1(u0.x, u0.y, m0.x, m0.y, t1);
        acc += flog2(fmaf(x1, t1, x0));
    }
    if (lane == 0 && chunk == NCHUNK - 1) {
        const float x0 = x[0], x1 = x[1];
        const int offz = 2 * (KM1 - 1);
        const f32x2 uz = *(const f32x2*)(u_row + offz);
        const f32x2 mz = *(const f32x2*)(msp + offz);
        float tz; CALC1(uz.x, uz.y, mz.x, mz.y, tz);
        acc += flog2(fmaf(x1, tz, x0));
    }

    // wave reduce
    #pragma unroll
    for (int off = 32; off >= 1; off >>= 1) acc += __shfl_down(acc, off);

    __shared__ float ssum[4];
    if (lane == 0) ssum[wave] = acc;
    __syncthreads();
    if (threadIdx.x == 0)
        ws[blockIdx.x] = ssum[0] + ssum[1] + ssum[2] + ssum[3];   // no atomic, no pre-zero
}

extern "C" void kernel_launch(void* const* d_in, const int* in_sizes, int n_in,
                              void* d_out, int out_size, void* d_ws, size_t ws_size,
                              hipStream_t stream) {
    const float* x  = (const float*)d_in[0];
    const float* ms = (const float*)d_in[1];
    const float* u  = (const float*)d_in[2];

    float* ws = (float*)d_ws;   // NBLK floats = 16 KB

    dim3 grid(NBLK);            // 4096 blocks
    terp_kernel<<<grid, 256, 0, stream>>>(x, ms, u, ws);

    final_reduce_kernel<<<1, 256, 0, stream>>>(ws, (float*)d_out);
}

// Round 11
// 46.815 us; speedup vs baseline: 1.8271x; 1.8271x over previous
//
#include <hip/hip_runtime.h>

static constexpr int KM1   = 1048575;      // elements per row, kk in [0, KM1)
static constexpr int M_S   = 32;
static constexpr int BSPAN = 1024;         // elements per block
static constexpr int WSPAN = 256;          // elements per wave (4 per lane)
static constexpr int NBLK  = 1024;         // BSPAN*NBLK = 1048576 (1 phantom elem)
static constexpr int EL    = KM1 - 1;      // last valid element index (1048574)

typedef float f32x2 __attribute__((ext_vector_type(2)));

#if __has_builtin(__builtin_amdgcn_logf)
__device__ __forceinline__ float flog2(float x) { return __builtin_amdgcn_logf(x); }
#else
__device__ __forceinline__ float flog2(float x) { float r; asm("v_log_f32 %0, %1" : "=v"(r) : "v"(x)); return r; }
#endif
#if __has_builtin(__builtin_amdgcn_exp2f)
__device__ __forceinline__ float fexp2(float x) { return __builtin_amdgcn_exp2f(x); }
#else
__device__ __forceinline__ float fexp2(float x) { float r; asm("v_exp_f32 %0, %1" : "=v"(r) : "v"(x)); return r; }
#endif

__global__ void final_reduce_kernel(const float* __restrict__ ws, float* __restrict__ out) {
    constexpr float LN2 = 0.69314718055994530942f;
    const int lane = threadIdx.x & 63;
    const int wave = threadIdx.x >> 6;
    float v = 0.0f;
    #pragma unroll
    for (int j = 0; j < NBLK / 256; ++j) v += ws[threadIdx.x + 256 * j];
    #pragma unroll
    for (int off = 32; off >= 1; off >>= 1) v += __shfl_down(v, off);
    __shared__ float s4[4];
    if (lane == 0) s4[wave] = v;
    __syncthreads();
    if (threadIdx.x == 0)
        out[0] = (s4[0] + s4[1] + s4[2] + s4[3]) * (-LN2 / (float)M_S);
}

__global__ __launch_bounds__(256, 4) void terp_kernel(
    const float* __restrict__ x,
    const float* __restrict__ ms,
    const float* __restrict__ u,
    float* __restrict__ ws)
{
    const int lane = threadIdx.x & 63;
    const int wave = threadIdx.x >> 6;
    const int base = blockIdx.x * BSPAN + wave * WSPAN;
    const int e0   = base + 4 * lane;

    // clamped float-offsets of this lane's 4 element-pairs and the wave-edge elem
    const int o0 = 2 * min(e0,     EL);
    const int o1 = 2 * min(e0 + 1, EL);
    const int o2 = 2 * min(e0 + 2, EL);
    const int o3 = 2 * min(e0 + 3, EL);
    const int oE = 2 * min(base + WSPAN, EL);

    const bool ragged = (base == (NBLK - 1) * BSPAN + 3 * WSPAN);  // last wave: elem 1048575 is phantom
    const bool xw     = (blockIdx.x == 0) && (wave == 0);          // owns global elem 0

    constexpr float LN2  = 0.69314718055994530942f;
    constexpr float invT = 1.0f / (2.5f * 0.9999f);
    constexpr float c_ms = invT / LN2;

    float x0 = 0.0f, x1 = 0.0f;
    if (xw || ragged) { x0 = x[0]; x1 = x[1]; }

    // ms is m-invariant: precompute dm = c_ms*(ms1-ms0) once, reuse for all 32 m
    float dm0, dm1, dm2, dm3, dmE;
    {
        f32x2 mp;
        mp = *(const f32x2*)(ms + o0); dm0 = c_ms * (mp.y - mp.x);
        mp = *(const f32x2*)(ms + o1); dm1 = c_ms * (mp.y - mp.x);
        mp = *(const f32x2*)(ms + o2); dm2 = c_ms * (mp.y - mp.x);
        mp = *(const f32x2*)(ms + o3); dm3 = c_ms * (mp.y - mp.x);
        mp = *(const f32x2*)(ms + oE); dmE = c_ms * (mp.y - mp.x);
    }

    float acc = 0.0f;   // log2 units

#define LOADU(P, U0_, U1_, U2_, U3_, UE_) do { \
        U0_ = *(const f32x2*)((P) + o0); \
        U1_ = *(const f32x2*)((P) + o1); \
        U2_ = *(const f32x2*)((P) + o2); \
        U3_ = *(const f32x2*)((P) + o3); \
        UE_ = *(const f32x2*)((P) + oE); \
    } while (0)

#define CALCT(U_, dm_, t_) do { \
        const float a_ = flog2(-flog2((U_).x)) - flog2(-flog2((U_).y)); \
        (t_) = fexp2(fmaf(invT, a_, dm_)); \
    } while (0)

#define COMPUTE(U0_, U1_, U2_, U3_, UE_) do { \
        float t0_, t1_, t2_, t3_, tE_; \
        CALCT(U0_, dm0, t0_); CALCT(U1_, dm1, t1_); \
        CALCT(U2_, dm2, t2_); CALCT(U3_, dm3, t3_); \
        CALCT(UE_, dmE, tE_); \
        const float r_ = (lane == 0) ? tE_ : t0_; \
        const float v_ = __shfl(r_, (lane + 1) & 63); \
        const float selfP_ = (1.0f + t0_) * (1.0f + t1_) * (1.0f + t2_) * (1.0f + t3_); \
        const float coupP_ = fmaf(t0_, t1_, 1.0f) * fmaf(t1_, t2_, 1.0f) * \
                             fmaf(t2_, t3_, 1.0f) * fmaf(t3_, v_, 1.0f); \
        acc = fmaf(-2.0f, flog2(selfP_), acc + flog2(coupP_)); \
        if (xw && lane == 0) acc += flog2(fmaf(x1, t0_, x0)); \
        if (ragged && lane == 63) \
            acc += 2.0f * flog2(1.0f + t2_) - 2.0f * flog2(fmaf(t2_, t2_, 1.0f)) \
                 + flog2(fmaf(x1, t2_, x0)); \
    } while (0)
    // ragged lane63: t3_ and v_ both alias elem 1048574 (clamped). Generic terms added
    // -2*log2(1+t2) [phantom self] and +2*log2(1+t2^2) [phantom couplings]; the correction
    // removes them and adds the (s_last, x) boundary numerator.

    const size_t RS = 2 * (size_t)KM1;   // row stride in floats
    f32x2 A0,A1,A2,A3,AE, B0,B1,B2,B3,BE, C0,C1,C2,C3,CE, D0,D1,D2,D3,DE;

    const float* pm = u;
    LOADU(pm, A0,A1,A2,A3,AE); pm += RS;
    LOADU(pm, B0,B1,B2,B3,BE); pm += RS;
    LOADU(pm, C0,C1,C2,C3,CE); pm += RS;
    LOADU(pm, D0,D1,D2,D3,DE); pm += RS;

    #pragma unroll 1
    for (int mi = 0; mi < 7; ++mi) {
        COMPUTE(A0,A1,A2,A3,AE); LOADU(pm, A0,A1,A2,A3,AE); pm += RS;
        COMPUTE(B0,B1,B2,B3,BE); LOADU(pm, B0,B1,B2,B3,BE); pm += RS;
        COMPUTE(C0,C1,C2,C3,CE); LOADU(pm, C0,C1,C2,C3,CE); pm += RS;
        COMPUTE(D0,D1,D2,D3,DE); LOADU(pm, D0,D1,D2,D3,DE); pm += RS;
    }
    COMPUTE(A0,A1,A2,A3,AE);
    COMPUTE(B0,B1,B2,B3,BE);
    COMPUTE(C0,C1,C2,C3,CE);
    COMPUTE(D0,D1,D2,D3,DE);

    // wave reduce
    #pragma unroll
    for (int off = 32; off >= 1; off >>= 1) acc += __shfl_down(acc, off);

    __shared__ float ssum[4];
    if (lane == 0) ssum[wave] = acc;
    __syncthreads();
    if (threadIdx.x == 0)
        ws[blockIdx.x] = ssum[0] + ssum[1] + ssum[2] + ssum[3];
}

extern "C" void kernel_launch(void* const* d_in, const int* in_sizes, int n_in,
                              void* d_out, int out_size, void* d_ws, size_t ws_size,
                              hipStream_t stream) {
    const float* x  = (const float*)d_in[0];
    const float* ms = (const float*)d_in[1];
    const float* u  = (const float*)d_in[2];

    float* ws = (float*)d_ws;   // NBLK floats = 4 KB

    terp_kernel<<<dim3(NBLK), 256, 0, stream>>>(x, ms, u, ws);
    final_reduce_kernel<<<1, 256, 0, stream>>>(ws, (float*)d_out);
}